// Round 1
// baseline (718.493 us; speedup 1.0000x reference)
//
#include <hip/hip_runtime.h>
#include <hip/hip_bf16.h>
#include <math.h>

#define DIMV 256
#define HV 8
#define DV 32

static __device__ __forceinline__ unsigned short f2bf(float f) {
    unsigned x = __float_as_uint(f);
    x += 0x7FFF + ((x >> 16) & 1);   // round-to-nearest-even
    return (unsigned short)(x >> 16);
}
static __device__ __forceinline__ float bf2f(unsigned short u) {
    return __uint_as_float(((unsigned)u) << 16);
}

// ---------------- CSR build ----------------

__global__ void zero_i32(int* __restrict__ p, int n) {
    int i = blockIdx.x * blockDim.x + threadIdx.x;
    if (i < n) p[i] = 0;
}

__global__ void count_deg(const int* __restrict__ dst, int* __restrict__ deg, int E) {
    int i = blockIdx.x * blockDim.x + threadIdx.x;
    if (i < E) atomicAdd(&deg[dst[i]], 1);
}

__global__ void scan_deg(const int* __restrict__ deg, int* __restrict__ offsets,
                         int* __restrict__ cursor, int n) {
    __shared__ int partial[256];
    int t = threadIdx.x;
    int chunk = (n + 255) / 256;
    int lo = t * chunk; if (lo > n) lo = n;
    int hi = lo + chunk; if (hi > n) hi = n;
    int s = 0;
    for (int i = lo; i < hi; ++i) s += deg[i];
    partial[t] = s;
    __syncthreads();
    if (t == 0) {
        int r = 0;
        for (int i = 0; i < 256; ++i) { int v = partial[i]; partial[i] = r; r += v; }
    }
    __syncthreads();
    int run = partial[t];
    for (int i = lo; i < hi; ++i) { offsets[i] = run; cursor[i] = run; run += deg[i]; }
    if (t == 255) offsets[n] = run;
}

__global__ void scatter_edges(const int* __restrict__ src, const int* __restrict__ dst,
                              int* __restrict__ cursor, int* __restrict__ perm_src, int E) {
    int i = blockIdx.x * blockDim.x + threadIdx.x;
    if (i < E) {
        int pos = atomicAdd(&cursor[dst[i]], 1);
        perm_src[pos] = src[i];
    }
}

// ---------------- GEMM: C = A @ W^T + bias  (A[M,256], W[256,256] row-major) ----------------

#define BM 64
#define BN 64
#define BK 16
#define LDSP (BM + 4)

__global__ __launch_bounds__(256)
void gemm_qkv(const float* __restrict__ x,
              const float* __restrict__ Wq, const float* __restrict__ bq,
              const float* __restrict__ Wk, const float* __restrict__ bk,
              const float* __restrict__ Wv, const float* __restrict__ bv,
              unsigned short* __restrict__ Q, unsigned short* __restrict__ Kk,
              unsigned short* __restrict__ V, int M) {
    const float* W; const float* bias; unsigned short* out;
    if (blockIdx.z == 0)      { W = Wq; bias = bq; out = Q;  }
    else if (blockIdx.z == 1) { W = Wk; bias = bk; out = Kk; }
    else                      { W = Wv; bias = bv; out = V;  }

    __shared__ float As[BK][LDSP];
    __shared__ float Bs[BK][LDSP];
    int tid = threadIdx.x;
    int row0 = blockIdx.x * BM, col0 = blockIdx.y * BN;
    int tx = tid & 15, ty = tid >> 4;
    int lr = tid >> 2, lk = (tid & 3) * 4;
    float acc[4][4] = {};

    const float* aptr = x + (size_t)min(row0 + lr, M - 1) * DIMV + lk;
    const float* bptr = W + (size_t)(col0 + lr) * DIMV + lk;

    for (int k0 = 0; k0 < DIMV; k0 += BK) {
        float4 av = *(const float4*)(aptr + k0);
        float4 bw = *(const float4*)(bptr + k0);
        As[lk + 0][lr] = av.x; As[lk + 1][lr] = av.y; As[lk + 2][lr] = av.z; As[lk + 3][lr] = av.w;
        Bs[lk + 0][lr] = bw.x; Bs[lk + 1][lr] = bw.y; Bs[lk + 2][lr] = bw.z; Bs[lk + 3][lr] = bw.w;
        __syncthreads();
#pragma unroll
        for (int k = 0; k < BK; ++k) {
            float4 a = *(const float4*)(&As[k][ty * 4]);
            float4 b = *(const float4*)(&Bs[k][tx * 4]);
            float ar[4] = {a.x, a.y, a.z, a.w};
            float br[4] = {b.x, b.y, b.z, b.w};
#pragma unroll
            for (int i = 0; i < 4; ++i)
#pragma unroll
                for (int j = 0; j < 4; ++j)
                    acc[i][j] = fmaf(ar[i], br[j], acc[i][j]);
        }
        __syncthreads();
    }

    float bv0 = bias[col0 + tx * 4 + 0], bv1 = bias[col0 + tx * 4 + 1];
    float bv2 = bias[col0 + tx * 4 + 2], bv3 = bias[col0 + tx * 4 + 3];
#pragma unroll
    for (int i = 0; i < 4; ++i) {
        int row = row0 + ty * 4 + i;
        if (row < M) {
            ushort4 o;
            o.x = f2bf(acc[i][0] + bv0);
            o.y = f2bf(acc[i][1] + bv1);
            o.z = f2bf(acc[i][2] + bv2);
            o.w = f2bf(acc[i][3] + bv3);
            *(ushort4*)(out + (size_t)row * DIMV + col0 + tx * 4) = o;
        }
    }
}

__global__ __launch_bounds__(256)
void gemm_o(const float* __restrict__ A, const float* __restrict__ W,
            const float* __restrict__ bias, float* __restrict__ C, int M) {
    __shared__ float As[BK][LDSP];
    __shared__ float Bs[BK][LDSP];
    int tid = threadIdx.x;
    int row0 = blockIdx.x * BM, col0 = blockIdx.y * BN;
    int tx = tid & 15, ty = tid >> 4;
    int lr = tid >> 2, lk = (tid & 3) * 4;
    float acc[4][4] = {};

    const float* aptr = A + (size_t)min(row0 + lr, M - 1) * DIMV + lk;
    const float* bptr = W + (size_t)(col0 + lr) * DIMV + lk;

    for (int k0 = 0; k0 < DIMV; k0 += BK) {
        float4 av = *(const float4*)(aptr + k0);
        float4 bw = *(const float4*)(bptr + k0);
        As[lk + 0][lr] = av.x; As[lk + 1][lr] = av.y; As[lk + 2][lr] = av.z; As[lk + 3][lr] = av.w;
        Bs[lk + 0][lr] = bw.x; Bs[lk + 1][lr] = bw.y; Bs[lk + 2][lr] = bw.z; Bs[lk + 3][lr] = bw.w;
        __syncthreads();
#pragma unroll
        for (int k = 0; k < BK; ++k) {
            float4 a = *(const float4*)(&As[k][ty * 4]);
            float4 b = *(const float4*)(&Bs[k][tx * 4]);
            float ar[4] = {a.x, a.y, a.z, a.w};
            float br[4] = {b.x, b.y, b.z, b.w};
#pragma unroll
            for (int i = 0; i < 4; ++i)
#pragma unroll
                for (int j = 0; j < 4; ++j)
                    acc[i][j] = fmaf(ar[i], br[j], acc[i][j]);
        }
        __syncthreads();
    }

    float bv0 = bias[col0 + tx * 4 + 0], bv1 = bias[col0 + tx * 4 + 1];
    float bv2 = bias[col0 + tx * 4 + 2], bv3 = bias[col0 + tx * 4 + 3];
#pragma unroll
    for (int i = 0; i < 4; ++i) {
        int row = row0 + ty * 4 + i;
        if (row < M) {
            float4 o = make_float4(acc[i][0] + bv0, acc[i][1] + bv1,
                                   acc[i][2] + bv2, acc[i][3] + bv3);
            *(float4*)(C + (size_t)row * DIMV + col0 + tx * 4) = o;
        }
    }
}

// ---------------- per-node edge-softmax attention ----------------
// one wave per dst node; 64 lanes = 8 heads x 8 lanes; each lane owns 4 d-elems.

__global__ __launch_bounds__(256)
void node_attn(const unsigned short* __restrict__ Q, const unsigned short* __restrict__ K,
               const unsigned short* __restrict__ V,
               const int* __restrict__ offsets, const int* __restrict__ perm_src,
               float* __restrict__ attn, int N) {
    int wid = (int)((blockIdx.x * blockDim.x + threadIdx.x) >> 6);
    if (wid >= N) return;
    int lane = threadIdx.x & 63;
    int col = (lane >> 3) * DV + (lane & 7) * 4;
    const float rsD = 0.17677669529663687f; // 1/sqrt(32)

    ushort4 kr = *(const ushort4*)(K + (size_t)wid * DIMV + col);
    float k0 = bf2f(kr.x), k1 = bf2f(kr.y), k2 = bf2f(kr.z), k3 = bf2f(kr.w);

    float m = -INFINITY, l = 0.f, a0 = 0.f, a1 = 0.f, a2 = 0.f, a3 = 0.f;
    int e0 = offsets[wid], e1 = offsets[wid + 1];
    for (int p = e0; p < e1; ++p) {
        int s = perm_src[p];
        ushort4 qr = *(const ushort4*)(Q + (size_t)s * DIMV + col);
        float d = bf2f(qr.x) * k0 + bf2f(qr.y) * k1 + bf2f(qr.z) * k2 + bf2f(qr.w) * k3;
        d += __shfl_xor(d, 1);
        d += __shfl_xor(d, 2);
        d += __shfl_xor(d, 4);
        float sc = d * rsD;
        float mn = fmaxf(m, sc);
        float scale = __expf(m - mn);   // first iter: exp(-inf)=0
        float pe = __expf(sc - mn);
        ushort4 vr = *(const ushort4*)(V + (size_t)s * DIMV + col);
        l = l * scale + pe;
        a0 = a0 * scale + pe * bf2f(vr.x);
        a1 = a1 * scale + pe * bf2f(vr.y);
        a2 = a2 * scale + pe * bf2f(vr.z);
        a3 = a3 * scale + pe * bf2f(vr.w);
        m = mn;
    }
    float inv = (l > 0.f) ? 1.f / l : 0.f;
    float4 o = make_float4(a0 * inv, a1 * inv, a2 * inv, a3 * inv);
    *(float4*)(attn + (size_t)wid * DIMV + col) = o;
}

// ---------------- launcher ----------------

extern "C" void kernel_launch(void* const* d_in, const int* in_sizes, int n_in,
                              void* d_out, int out_size, void* d_ws, size_t ws_size,
                              hipStream_t stream) {
    const float* x  = (const float*)d_in[0];
    const float* Wq = (const float*)d_in[1];
    const float* bq = (const float*)d_in[2];
    const float* Wk = (const float*)d_in[3];
    const float* bk = (const float*)d_in[4];
    const float* Wv = (const float*)d_in[5];
    const float* bv = (const float*)d_in[6];
    const float* Wo = (const float*)d_in[7];
    const float* bo = (const float*)d_in[8];
    const int* src  = (const int*)d_in[9];
    const int* dst  = (const int*)d_in[10];
    int N = in_sizes[0] / DIMV;
    int E = in_sizes[9];
    float* out = (float*)d_out;

    char* p = (char*)d_ws;
    auto alloc = [&](size_t bytes) {
        char* r = p;
        p += (bytes + 255) & ~(size_t)255;
        return r;
    };
    unsigned short* Q  = (unsigned short*)alloc((size_t)N * DIMV * 2);
    unsigned short* Kk = (unsigned short*)alloc((size_t)N * DIMV * 2);
    unsigned short* V  = (unsigned short*)alloc((size_t)N * DIMV * 2);
    float* attn        = (float*)alloc((size_t)N * DIMV * 4);
    int* deg           = (int*)alloc((size_t)N * 4);
    int* offsets       = (int*)alloc((size_t)(N + 1) * 4);
    int* cursor        = (int*)alloc((size_t)N * 4);
    int* perm_src      = (int*)alloc((size_t)E * 4);

    // CSR build (independent of GEMMs; stream-ordered anyway)
    zero_i32<<<(N + 255) / 256, 256, 0, stream>>>(deg, N);
    count_deg<<<(E + 255) / 256, 256, 0, stream>>>(dst, deg, E);
    scan_deg<<<1, 256, 0, stream>>>(deg, offsets, cursor, N);
    scatter_edges<<<(E + 255) / 256, 256, 0, stream>>>(src, dst, cursor, perm_src, E);

    dim3 gq((N + BM - 1) / BM, DIMV / BN, 3);
    gemm_qkv<<<gq, 256, 0, stream>>>(x, Wq, bq, Wk, bk, Wv, bv, Q, Kk, V, N);

    node_attn<<<(int)(((size_t)N * 64 + 255) / 256), 256, 0, stream>>>(Q, Kk, V, offsets, perm_src, attn, N);

    dim3 go((N + BM - 1) / BM, DIMV / BN);
    gemm_o<<<go, 256, 0, stream>>>(attn, Wo, bo, out, N);
}

// Round 2
// 396.140 us; speedup vs baseline: 1.8137x; 1.8137x over previous
//
#include <hip/hip_runtime.h>
#include <hip/hip_bf16.h>
#include <math.h>

#define DIMV 256
#define HV 8
#define DV 32

typedef __attribute__((ext_vector_type(8))) short bf16x8;
typedef __attribute__((ext_vector_type(4))) float f32x4;

static __device__ __forceinline__ unsigned short f2bf(float f) {
    unsigned x = __float_as_uint(f);
    x += 0x7FFF + ((x >> 16) & 1);   // round-to-nearest-even
    return (unsigned short)(x >> 16);
}
static __device__ __forceinline__ float bf2f(unsigned short u) {
    return __uint_as_float(((unsigned)u) << 16);
}

// ---------------- f32 -> bf16 conversion ----------------

__global__ void cvt_f32_bf16(const float* __restrict__ in, unsigned short* __restrict__ out, int n4) {
    int i = blockIdx.x * blockDim.x + threadIdx.x;
    int stride = gridDim.x * blockDim.x;
    for (; i < n4; i += stride) {
        float4 v = ((const float4*)in)[i];
        ushort4 o;
        o.x = f2bf(v.x); o.y = f2bf(v.y); o.z = f2bf(v.z); o.w = f2bf(v.w);
        ((ushort4*)out)[i] = o;
    }
}

// ---------------- CSR build ----------------

__global__ void zero_i32(int* __restrict__ p, int n) {
    int i = blockIdx.x * blockDim.x + threadIdx.x;
    if (i < n) p[i] = 0;
}

__global__ void count_deg(const int* __restrict__ dst, int* __restrict__ deg, int E) {
    int i = blockIdx.x * blockDim.x + threadIdx.x;
    if (i < E) atomicAdd(&deg[dst[i]], 1);
}

__global__ void block_sum(const int* __restrict__ deg, int* __restrict__ bsum, int n) {
    __shared__ int sm[256];
    int i = blockIdx.x * 256 + threadIdx.x;
    sm[threadIdx.x] = (i < n) ? deg[i] : 0;
    __syncthreads();
    for (int s = 128; s > 0; s >>= 1) {
        if (threadIdx.x < s) sm[threadIdx.x] += sm[threadIdx.x + s];
        __syncthreads();
    }
    if (threadIdx.x == 0) bsum[blockIdx.x] = sm[0];
}

__global__ void scan_bsum(int* __restrict__ bsum, int nb) {
    if (threadIdx.x == 0) {
        int r = 0;
        for (int i = 0; i < nb; ++i) { int v = bsum[i]; bsum[i] = r; r += v; }
    }
}

__global__ void scan_final(const int* __restrict__ deg, const int* __restrict__ bsum,
                           int* __restrict__ offsets, int* __restrict__ cursor, int n) {
    __shared__ int sm[256];
    int i = blockIdx.x * 256 + threadIdx.x;
    int v = (i < n) ? deg[i] : 0;
    sm[threadIdx.x] = v;
    __syncthreads();
    for (int s = 1; s < 256; s <<= 1) {
        int t = (threadIdx.x >= s) ? sm[threadIdx.x - s] : 0;
        __syncthreads();
        sm[threadIdx.x] += t;
        __syncthreads();
    }
    int excl = sm[threadIdx.x] - v + bsum[blockIdx.x];
    if (i < n) { offsets[i] = excl; cursor[i] = excl; }
    if (i == n - 1) offsets[n] = excl + v;
}

__global__ void scatter_edges(const int* __restrict__ src, const int* __restrict__ dst,
                              int* __restrict__ cursor, int* __restrict__ perm_src, int E) {
    int i = blockIdx.x * blockDim.x + threadIdx.x;
    if (i < E) {
        int pos = atomicAdd(&cursor[dst[i]], 1);
        perm_src[pos] = src[i];
    }
}

// ---------------- MFMA GEMM: C = A @ W^T + bias ----------------
// A [M,256] bf16 row-major, W [256,256] bf16 row-major (both K-contiguous).
// LDS-free: each lane loads MFMA fragments directly from global (L2/L3-resident).
// Block: 256 threads = 4 waves stacked in M. Wave tile: 32 rows x 64 cols.

template<bool BF16OUT>
static __device__ __forceinline__
void gemm_body(const unsigned short* __restrict__ A,
               const unsigned short* __restrict__ W,
               const float* __restrict__ bias,
               void* __restrict__ C, int M) {
    int tid = threadIdx.x;
    int lane = tid & 63;
    int w = tid >> 6;
    int row0 = blockIdx.x * 128 + w * 32;
    int col0 = blockIdx.y * 64;
    int lrow = lane & 15;
    int lk = (lane >> 4) * 8;

    f32x4 acc[2][4] = {};

    int ra0 = min(row0 + lrow, M - 1);
    int ra1 = min(row0 + 16 + lrow, M - 1);
    const unsigned short* a0p = A + (size_t)ra0 * DIMV + lk;
    const unsigned short* a1p = A + (size_t)ra1 * DIMV + lk;
    const unsigned short* bp  = W + (size_t)(col0 + lrow) * DIMV + lk;

#pragma unroll 2
    for (int k0 = 0; k0 < DIMV; k0 += 32) {
        bf16x8 a0 = *(const bf16x8*)(a0p + k0);
        bf16x8 a1 = *(const bf16x8*)(a1p + k0);
#pragma unroll
        for (int n = 0; n < 4; ++n) {
            bf16x8 b = *(const bf16x8*)(bp + (size_t)n * 16 * DIMV + k0);
            acc[0][n] = __builtin_amdgcn_mfma_f32_16x16x32_bf16(a0, b, acc[0][n], 0, 0, 0);
            acc[1][n] = __builtin_amdgcn_mfma_f32_16x16x32_bf16(a1, b, acc[1][n], 0, 0, 0);
        }
    }

    float bvals[4];
#pragma unroll
    for (int n = 0; n < 4; ++n) bvals[n] = bias[col0 + n * 16 + lrow];

    int rbase = (lane >> 4) * 4;
#pragma unroll
    for (int mf = 0; mf < 2; ++mf) {
#pragma unroll
        for (int r = 0; r < 4; ++r) {
            int row = row0 + mf * 16 + rbase + r;
            if (row < M) {
#pragma unroll
                for (int n = 0; n < 4; ++n) {
                    float val = acc[mf][n][r] + bvals[n];
                    int col = col0 + n * 16 + lrow;
                    if (BF16OUT)
                        ((unsigned short*)C)[(size_t)row * DIMV + col] = f2bf(val);
                    else
                        ((float*)C)[(size_t)row * DIMV + col] = val;
                }
            }
        }
    }
}

__global__ __launch_bounds__(256)
void gemm_qkv(const unsigned short* __restrict__ Xb,
              const unsigned short* __restrict__ Wqb, const float* __restrict__ bq,
              const unsigned short* __restrict__ Wkb, const float* __restrict__ bk,
              const unsigned short* __restrict__ Wvb, const float* __restrict__ bv,
              unsigned short* __restrict__ Q, unsigned short* __restrict__ K,
              unsigned short* __restrict__ V, int M) {
    const unsigned short* W; const float* bias; unsigned short* out;
    if (blockIdx.z == 0)      { W = Wqb; bias = bq; out = Q; }
    else if (blockIdx.z == 1) { W = Wkb; bias = bk; out = K; }
    else                      { W = Wvb; bias = bv; out = V; }
    gemm_body<true>(Xb, W, bias, out, M);
}

__global__ __launch_bounds__(256)
void gemm_out(const unsigned short* __restrict__ A, const unsigned short* __restrict__ W,
              const float* __restrict__ bias, float* __restrict__ C, int M) {
    gemm_body<false>(A, W, bias, C, M);
}

// ---------------- per-node edge-softmax attention ----------------
// one wave per dst node; 64 lanes = 8 heads x 8 lanes; lane owns 4 d-elems.
// 2 edges per iteration with independent online-softmax states (ILP).

__global__ __launch_bounds__(256)
void node_attn(const unsigned short* __restrict__ Q, const unsigned short* __restrict__ K,
               const unsigned short* __restrict__ V,
               const int* __restrict__ offsets, const int* __restrict__ perm_src,
               unsigned short* __restrict__ attn, int N) {
    int wid = blockIdx.x * (blockDim.x >> 6) + (threadIdx.x >> 6);
    if (wid >= N) return;
    int lane = threadIdx.x & 63;
    int col = (lane >> 3) * DV + (lane & 7) * 4;
    const float rsD = 0.17677669529663687f; // 1/sqrt(32)

    ushort4 kr = *(const ushort4*)(K + (size_t)wid * DIMV + col);
    float k0 = bf2f(kr.x) * rsD, k1 = bf2f(kr.y) * rsD;
    float k2 = bf2f(kr.z) * rsD, k3 = bf2f(kr.w) * rsD;

    float mA = -INFINITY, lA = 0.f, aA0 = 0.f, aA1 = 0.f, aA2 = 0.f, aA3 = 0.f;
    float mB = -INFINITY, lB = 0.f, aB0 = 0.f, aB1 = 0.f, aB2 = 0.f, aB3 = 0.f;

    int e0 = offsets[wid], e1 = offsets[wid + 1];
    int p = e0;
    for (; p + 2 <= e1; p += 2) {
        int s0 = perm_src[p];
        int s1 = perm_src[p + 1];
        ushort4 q0 = *(const ushort4*)(Q + (size_t)s0 * DIMV + col);
        ushort4 q1 = *(const ushort4*)(Q + (size_t)s1 * DIMV + col);
        ushort4 v0 = *(const ushort4*)(V + (size_t)s0 * DIMV + col);
        ushort4 v1 = *(const ushort4*)(V + (size_t)s1 * DIMV + col);
        float d0 = bf2f(q0.x) * k0 + bf2f(q0.y) * k1 + bf2f(q0.z) * k2 + bf2f(q0.w) * k3;
        float d1 = bf2f(q1.x) * k0 + bf2f(q1.y) * k1 + bf2f(q1.z) * k2 + bf2f(q1.w) * k3;
        d0 += __shfl_xor(d0, 1); d0 += __shfl_xor(d0, 2); d0 += __shfl_xor(d0, 4);
        d1 += __shfl_xor(d1, 1); d1 += __shfl_xor(d1, 2); d1 += __shfl_xor(d1, 4);

        float mnA = fmaxf(mA, d0);
        float scA = __expf(mA - mnA);
        float peA = __expf(d0 - mnA);
        lA = lA * scA + peA;
        aA0 = aA0 * scA + peA * bf2f(v0.x);
        aA1 = aA1 * scA + peA * bf2f(v0.y);
        aA2 = aA2 * scA + peA * bf2f(v0.z);
        aA3 = aA3 * scA + peA * bf2f(v0.w);
        mA = mnA;

        float mnB = fmaxf(mB, d1);
        float scB = __expf(mB - mnB);
        float peB = __expf(d1 - mnB);
        lB = lB * scB + peB;
        aB0 = aB0 * scB + peB * bf2f(v1.x);
        aB1 = aB1 * scB + peB * bf2f(v1.y);
        aB2 = aB2 * scB + peB * bf2f(v1.z);
        aB3 = aB3 * scB + peB * bf2f(v1.w);
        mB = mnB;
    }
    if (p < e1) {
        int s0 = perm_src[p];
        ushort4 q0 = *(const ushort4*)(Q + (size_t)s0 * DIMV + col);
        ushort4 v0 = *(const ushort4*)(V + (size_t)s0 * DIMV + col);
        float d0 = bf2f(q0.x) * k0 + bf2f(q0.y) * k1 + bf2f(q0.z) * k2 + bf2f(q0.w) * k3;
        d0 += __shfl_xor(d0, 1); d0 += __shfl_xor(d0, 2); d0 += __shfl_xor(d0, 4);
        float mnA = fmaxf(mA, d0);
        float scA = __expf(mA - mnA);
        float peA = __expf(d0 - mnA);
        lA = lA * scA + peA;
        aA0 = aA0 * scA + peA * bf2f(v0.x);
        aA1 = aA1 * scA + peA * bf2f(v0.y);
        aA2 = aA2 * scA + peA * bf2f(v0.z);
        aA3 = aA3 * scA + peA * bf2f(v0.w);
        mA = mnA;
    }

    // merge states (guard exp(-inf - -inf) for empty states)
    float mn = fmaxf(mA, mB);
    float scA = (lA > 0.f) ? __expf(mA - mn) : 0.f;
    float scB = (lB > 0.f) ? __expf(mB - mn) : 0.f;
    float l = lA * scA + lB * scB;
    float o0 = aA0 * scA + aB0 * scB;
    float o1 = aA1 * scA + aB1 * scB;
    float o2 = aA2 * scA + aB2 * scB;
    float o3 = aA3 * scA + aB3 * scB;
    float inv = (l > 0.f) ? 1.f / l : 0.f;

    ushort4 o;
    o.x = f2bf(o0 * inv); o.y = f2bf(o1 * inv); o.z = f2bf(o2 * inv); o.w = f2bf(o3 * inv);
    *(ushort4*)(attn + (size_t)wid * DIMV + col) = o;
}

// ---------------- launcher ----------------

extern "C" void kernel_launch(void* const* d_in, const int* in_sizes, int n_in,
                              void* d_out, int out_size, void* d_ws, size_t ws_size,
                              hipStream_t stream) {
    const float* x  = (const float*)d_in[0];
    const float* Wq = (const float*)d_in[1];
    const float* bq = (const float*)d_in[2];
    const float* Wk = (const float*)d_in[3];
    const float* bk = (const float*)d_in[4];
    const float* Wv = (const float*)d_in[5];
    const float* bv = (const float*)d_in[6];
    const float* Wo = (const float*)d_in[7];
    const float* bo = (const float*)d_in[8];
    const int* src  = (const int*)d_in[9];
    const int* dst  = (const int*)d_in[10];
    int N = in_sizes[0] / DIMV;
    int E = in_sizes[9];
    float* out = (float*)d_out;

    char* p = (char*)d_ws;
    auto alloc = [&](size_t bytes) {
        char* r = p;
        p += (bytes + 255) & ~(size_t)255;
        return r;
    };
    unsigned short* Xb  = (unsigned short*)alloc((size_t)N * DIMV * 2);
    unsigned short* Wqb = (unsigned short*)alloc((size_t)DIMV * DIMV * 2);
    unsigned short* Wkb = (unsigned short*)alloc((size_t)DIMV * DIMV * 2);
    unsigned short* Wvb = (unsigned short*)alloc((size_t)DIMV * DIMV * 2);
    unsigned short* Wob = (unsigned short*)alloc((size_t)DIMV * DIMV * 2);
    unsigned short* Q   = (unsigned short*)alloc((size_t)N * DIMV * 2);
    unsigned short* K   = (unsigned short*)alloc((size_t)N * DIMV * 2);
    unsigned short* V   = (unsigned short*)alloc((size_t)N * DIMV * 2);
    unsigned short* attn= (unsigned short*)alloc((size_t)N * DIMV * 2);
    int* deg            = (int*)alloc((size_t)N * 4);
    int* offsets        = (int*)alloc((size_t)(N + 1) * 4);
    int* cursor         = (int*)alloc((size_t)N * 4);
    int* perm_src       = (int*)alloc((size_t)E * 4);
    int* bsum           = (int*)alloc((size_t)1024 * 4);

    // dtype conversions
    int n4x = N * DIMV / 4;
    cvt_f32_bf16<<<2048, 256, 0, stream>>>(x, Xb, n4x);
    int n4w = DIMV * DIMV / 4;
    cvt_f32_bf16<<<64, 256, 0, stream>>>(Wq, Wqb, n4w);
    cvt_f32_bf16<<<64, 256, 0, stream>>>(Wk, Wkb, n4w);
    cvt_f32_bf16<<<64, 256, 0, stream>>>(Wv, Wvb, n4w);
    cvt_f32_bf16<<<64, 256, 0, stream>>>(Wo, Wob, n4w);

    // CSR build
    int nb = (N + 255) / 256;
    zero_i32<<<nb, 256, 0, stream>>>(deg, N);
    count_deg<<<(E + 255) / 256, 256, 0, stream>>>(dst, deg, E);
    block_sum<<<nb, 256, 0, stream>>>(deg, bsum, N);
    scan_bsum<<<1, 64, 0, stream>>>(bsum, nb);
    scan_final<<<nb, 256, 0, stream>>>(deg, bsum, offsets, cursor, N);
    scatter_edges<<<(E + 255) / 256, 256, 0, stream>>>(src, dst, cursor, perm_src, E);

    // projections
    dim3 gq((N + 127) / 128, DIMV / 64, 3);
    gemm_qkv<<<gq, 256, 0, stream>>>(Xb, Wqb, bq, Wkb, bk, Wvb, bv, Q, K, V, N);

    // attention
    node_attn<<<(N + 3) / 4, 256, 0, stream>>>(Q, K, V, offsets, perm_src, attn, N);

    // output projection
    dim3 go((N + 127) / 128, DIMV / 64);
    gemm_out<<<go, 256, 0, stream>>>(attn, Wob, bo, out, N);
}

// Round 3
// 328.314 us; speedup vs baseline: 2.1884x; 1.2066x over previous
//
#include <hip/hip_runtime.h>
#include <hip/hip_bf16.h>
#include <math.h>

#define DIMV 256
#define DV 32

typedef __attribute__((ext_vector_type(8))) short bf16x8;
typedef __attribute__((ext_vector_type(4))) float f32x4;

static __device__ __forceinline__ unsigned short f2bf(float f) {
    unsigned x = __float_as_uint(f);
    x += 0x7FFF + ((x >> 16) & 1);   // round-to-nearest-even
    return (unsigned short)(x >> 16);
}
static __device__ __forceinline__ float bf2f(unsigned short u) {
    return __uint_as_float(((unsigned)u) << 16);
}

static __device__ __forceinline__ void async16(const void* g, void* lds) {
    __builtin_amdgcn_global_load_lds(
        (const __attribute__((address_space(1))) void*)g,
        (__attribute__((address_space(3))) void*)lds, 16, 0, 0);
}

// ---------------- weight f32 -> bf16 (all 4 matrices, one kernel) ----------------

__global__ void cvt_w(const float* __restrict__ Wq, const float* __restrict__ Wk,
                      const float* __restrict__ Wv, const float* __restrict__ Wo,
                      unsigned short* __restrict__ Wcat) {
    const float* W = blockIdx.y == 0 ? Wq : blockIdx.y == 1 ? Wk : blockIdx.y == 2 ? Wv : Wo;
    int i = blockIdx.x * 256 + threadIdx.x;          // float4 index, 16384 per matrix
    float4 v = ((const float4*)W)[i];
    ushort4 o;
    o.x = f2bf(v.x); o.y = f2bf(v.y); o.z = f2bf(v.z); o.w = f2bf(v.w);
    ((ushort4*)(Wcat + (size_t)blockIdx.y * 65536))[i] = o;
}

// ---------------- CSR build ----------------

__global__ void zero_i32(int* __restrict__ p, int n) {
    int i = blockIdx.x * blockDim.x + threadIdx.x;
    if (i < n) p[i] = 0;
}

__global__ void count_deg(const int* __restrict__ dst, int* __restrict__ deg, int E) {
    int i = blockIdx.x * blockDim.x + threadIdx.x;
    if (i < E) atomicAdd(&deg[dst[i]], 1);
}

__global__ void block_sum(const int* __restrict__ deg, int* __restrict__ bsum, int n) {
    __shared__ int sm[256];
    int i = blockIdx.x * 256 + threadIdx.x;
    sm[threadIdx.x] = (i < n) ? deg[i] : 0;
    __syncthreads();
    for (int s = 128; s > 0; s >>= 1) {
        if (threadIdx.x < s) sm[threadIdx.x] += sm[threadIdx.x + s];
        __syncthreads();
    }
    if (threadIdx.x == 0) bsum[blockIdx.x] = sm[0];
}

__global__ void scan_bsum(int* __restrict__ bsum, int nb) {
    if (threadIdx.x == 0) {
        int r = 0;
        for (int i = 0; i < nb; ++i) { int v = bsum[i]; bsum[i] = r; r += v; }
    }
}

__global__ void scan_final(const int* __restrict__ deg, const int* __restrict__ bsum,
                           int* __restrict__ offsets, int* __restrict__ cursor, int n) {
    __shared__ int sm[256];
    int i = blockIdx.x * 256 + threadIdx.x;
    int v = (i < n) ? deg[i] : 0;
    sm[threadIdx.x] = v;
    __syncthreads();
    for (int s = 1; s < 256; s <<= 1) {
        int t = (threadIdx.x >= s) ? sm[threadIdx.x - s] : 0;
        __syncthreads();
        sm[threadIdx.x] += t;
        __syncthreads();
    }
    int excl = sm[threadIdx.x] - v + bsum[blockIdx.x];
    if (i < n) { offsets[i] = excl; cursor[i] = excl; }
    if (i == n - 1) offsets[n] = excl + v;
}

__global__ void scatter_edges(const int* __restrict__ src, const int* __restrict__ dst,
                              int* __restrict__ cursor, int* __restrict__ perm_src, int E) {
    int i = blockIdx.x * blockDim.x + threadIdx.x;
    if (i < E) {
        int pos = atomicAdd(&cursor[dst[i]], 1);
        perm_src[pos] = src[i];
    }
}

// ---------------- fused MFMA GEMM: C[mat] = A @ W[mat]^T + b[mat] ----------------
// A [M,256] (f32 or bf16) row-major; Wcat [nmat][256][256] bf16 row-major.
// Block: 64 rows x (ntiles * 32 cols). 4 waves = 2 row-groups x 2 col-groups;
// wave tile = 32 rows x 16 cols. A strip lives in registers (read once);
// W tiles (32 cols x 256 K = 16 KB) double-buffered in LDS via global_load_lds,
// XOR-swizzled (pre-swizzled global source, swizzled ds_read -> conflict-free).

template<bool AF32, bool OF32>
__global__ __launch_bounds__(256, 4)
void gemm_fused(const void* __restrict__ Ain,
                const unsigned short* __restrict__ Wcat,
                const float* __restrict__ b0, const float* __restrict__ b1,
                const float* __restrict__ b2,
                void* __restrict__ Cout, int M, int ntiles) {
    __shared__ unsigned short Bls[2][32 * 256];   // 2 x 16 KB
    const int tid = threadIdx.x;
    const int w = tid >> 6, lane = tid & 63;
    const int rg = w >> 1, cg = w & 1;
    const int lrow = lane & 15, lkg = lane >> 4;
    const int row0 = blockIdx.x * 64;

    // ---- stage tile 0 (pre-swizzled source, linear LDS dest) ----
    {
        const char* gb = (const char*)Wcat;
        #pragma unroll
        for (int i = 0; i < 4; ++i) {
            unsigned o = (unsigned)(i * 4096 + w * 1024 + lane * 16);
            unsigned srcoff = o ^ (((o >> 9) & 7u) << 4);
            async16(gb + srcoff, (char*)&Bls[0][0] + (i * 4096 + w * 1024));
        }
    }

    // ---- load A strip into registers (32 rows/wave, fused f32->bf16) ----
    bf16x8 a[2][8];
    #pragma unroll
    for (int m = 0; m < 2; ++m) {
        int row = row0 + rg * 32 + m * 16 + lrow;
        row = min(row, M - 1);
        if (AF32) {
            const float* ap = (const float*)Ain + (size_t)row * DIMV + lkg * 8;
            #pragma unroll
            for (int k0 = 0; k0 < 8; ++k0) {
                float4 f0 = *(const float4*)(ap + k0 * 32);
                float4 f1 = *(const float4*)(ap + k0 * 32 + 4);
                bf16x8 r;
                r[0] = (short)f2bf(f0.x); r[1] = (short)f2bf(f0.y);
                r[2] = (short)f2bf(f0.z); r[3] = (short)f2bf(f0.w);
                r[4] = (short)f2bf(f1.x); r[5] = (short)f2bf(f1.y);
                r[6] = (short)f2bf(f1.z); r[7] = (short)f2bf(f1.w);
                a[m][k0] = r;
            }
        } else {
            const unsigned short* ap = (const unsigned short*)Ain + (size_t)row * DIMV + lkg * 8;
            #pragma unroll
            for (int k0 = 0; k0 < 8; ++k0)
                a[m][k0] = *(const bf16x8*)(ap + k0 * 32);
        }
    }
    __syncthreads();   // tile 0 staged (implicit vmcnt drain) + all waves ready

    const int c = cg * 16 + lrow;   // tile-local output col in [0,32)
    for (int t = 0; t < ntiles; ++t) {
        // prefetch tile t+1 into the other buffer
        if (t + 1 < ntiles) {
            const char* gb = (const char*)Wcat + (size_t)(t + 1) * 16384;
            #pragma unroll
            for (int i = 0; i < 4; ++i) {
                unsigned o = (unsigned)(i * 4096 + w * 1024 + lane * 16);
                unsigned srcoff = o ^ (((o >> 9) & 7u) << 4);
                async16(gb + srcoff, (char*)&Bls[(t + 1) & 1][0] + (i * 4096 + w * 1024));
            }
        }

        // compute tile t
        const char* bls = (const char*)&Bls[t & 1][0];
        f32x4 acc0 = {0.f, 0.f, 0.f, 0.f};
        f32x4 acc1 = {0.f, 0.f, 0.f, 0.f};
        #pragma unroll
        for (int k0 = 0; k0 < 8; ++k0) {
            unsigned lin = (unsigned)c * 512 + (unsigned)k0 * 64 + (unsigned)lkg * 16;
            unsigned addr = lin ^ (((unsigned)c & 7u) << 4);
            bf16x8 bf = *(const bf16x8*)(bls + addr);
            acc0 = __builtin_amdgcn_mfma_f32_16x16x32_bf16(a[0][k0], bf, acc0, 0, 0, 0);
            acc1 = __builtin_amdgcn_mfma_f32_16x16x32_bf16(a[1][k0], bf, acc1, 0, 0, 0);
        }

        int mat = t >> 3;   // 8 col-tiles per matrix
        const float* bp = (mat == 0) ? b0 : (mat == 1 ? b1 : b2);
        int gcol = ((t & 7) << 5) + c;
        float bias = bp[gcol];
        size_t obase = (size_t)mat * M * DIMV;
        #pragma unroll
        for (int m = 0; m < 2; ++m) {
            f32x4 av = m ? acc1 : acc0;
            #pragma unroll
            for (int r = 0; r < 4; ++r) {
                int row = row0 + rg * 32 + m * 16 + lkg * 4 + r;
                if (row < M) {
                    float val = av[r] + bias;
                    if (OF32)
                        ((float*)Cout)[obase + (size_t)row * DIMV + gcol] = val;
                    else
                        ((unsigned short*)Cout)[obase + (size_t)row * DIMV + gcol] = f2bf(val);
                }
            }
        }
        __syncthreads();   // tile t+1 staged; all waves done reading buf[t&1]
    }
}

// ---------------- per-node edge-softmax attention ----------------
// one wave per dst node; 64 lanes = 8 heads x 8 lanes; lane owns 4 d-elems.
// 2 edges per iteration with independent online-softmax states (ILP).

__global__ __launch_bounds__(256)
void node_attn(const unsigned short* __restrict__ Q, const unsigned short* __restrict__ K,
               const unsigned short* __restrict__ V,
               const int* __restrict__ offsets, const int* __restrict__ perm_src,
               unsigned short* __restrict__ attn, int N) {
    int wid = blockIdx.x * (blockDim.x >> 6) + (threadIdx.x >> 6);
    if (wid >= N) return;
    int lane = threadIdx.x & 63;
    int col = (lane >> 3) * DV + (lane & 7) * 4;
    const float rsD = 0.17677669529663687f; // 1/sqrt(32)

    ushort4 kr = *(const ushort4*)(K + (size_t)wid * DIMV + col);
    float k0 = bf2f(kr.x) * rsD, k1 = bf2f(kr.y) * rsD;
    float k2 = bf2f(kr.z) * rsD, k3 = bf2f(kr.w) * rsD;

    float mA = -INFINITY, lA = 0.f, aA0 = 0.f, aA1 = 0.f, aA2 = 0.f, aA3 = 0.f;
    float mB = -INFINITY, lB = 0.f, aB0 = 0.f, aB1 = 0.f, aB2 = 0.f, aB3 = 0.f;

    int e0 = offsets[wid], e1 = offsets[wid + 1];
    int p = e0;
    for (; p + 2 <= e1; p += 2) {
        int s0 = perm_src[p];
        int s1 = perm_src[p + 1];
        ushort4 q0 = *(const ushort4*)(Q + (size_t)s0 * DIMV + col);
        ushort4 q1 = *(const ushort4*)(Q + (size_t)s1 * DIMV + col);
        ushort4 v0 = *(const ushort4*)(V + (size_t)s0 * DIMV + col);
        ushort4 v1 = *(const ushort4*)(V + (size_t)s1 * DIMV + col);
        float d0 = bf2f(q0.x) * k0 + bf2f(q0.y) * k1 + bf2f(q0.z) * k2 + bf2f(q0.w) * k3;
        float d1 = bf2f(q1.x) * k0 + bf2f(q1.y) * k1 + bf2f(q1.z) * k2 + bf2f(q1.w) * k3;
        d0 += __shfl_xor(d0, 1); d0 += __shfl_xor(d0, 2); d0 += __shfl_xor(d0, 4);
        d1 += __shfl_xor(d1, 1); d1 += __shfl_xor(d1, 2); d1 += __shfl_xor(d1, 4);

        float mnA = fmaxf(mA, d0);
        float scA = __expf(mA - mnA);
        float peA = __expf(d0 - mnA);
        lA = lA * scA + peA;
        aA0 = aA0 * scA + peA * bf2f(v0.x);
        aA1 = aA1 * scA + peA * bf2f(v0.y);
        aA2 = aA2 * scA + peA * bf2f(v0.z);
        aA3 = aA3 * scA + peA * bf2f(v0.w);
        mA = mnA;

        float mnB = fmaxf(mB, d1);
        float scB = __expf(mB - mnB);
        float peB = __expf(d1 - mnB);
        lB = lB * scB + peB;
        aB0 = aB0 * scB + peB * bf2f(v1.x);
        aB1 = aB1 * scB + peB * bf2f(v1.y);
        aB2 = aB2 * scB + peB * bf2f(v1.z);
        aB3 = aB3 * scB + peB * bf2f(v1.w);
        mB = mnB;
    }
    if (p < e1) {
        int s0 = perm_src[p];
        ushort4 q0 = *(const ushort4*)(Q + (size_t)s0 * DIMV + col);
        ushort4 v0 = *(const ushort4*)(V + (size_t)s0 * DIMV + col);
        float d0 = bf2f(q0.x) * k0 + bf2f(q0.y) * k1 + bf2f(q0.z) * k2 + bf2f(q0.w) * k3;
        d0 += __shfl_xor(d0, 1); d0 += __shfl_xor(d0, 2); d0 += __shfl_xor(d0, 4);
        float mnA = fmaxf(mA, d0);
        float scA = __expf(mA - mnA);
        float peA = __expf(d0 - mnA);
        lA = lA * scA + peA;
        aA0 = aA0 * scA + peA * bf2f(v0.x);
        aA1 = aA1 * scA + peA * bf2f(v0.y);
        aA2 = aA2 * scA + peA * bf2f(v0.z);
        aA3 = aA3 * scA + peA * bf2f(v0.w);
        mA = mnA;
    }

    // merge the two states
    float mn = fmaxf(mA, mB);
    float scA = (lA > 0.f) ? __expf(mA - mn) : 0.f;
    float scB = (lB > 0.f) ? __expf(mB - mn) : 0.f;
    float l = lA * scA + lB * scB;
    float o0 = aA0 * scA + aB0 * scB;
    float o1 = aA1 * scA + aB1 * scB;
    float o2 = aA2 * scA + aB2 * scB;
    float o3 = aA3 * scA + aB3 * scB;
    float inv = (l > 0.f) ? 1.f / l : 0.f;

    ushort4 o;
    o.x = f2bf(o0 * inv); o.y = f2bf(o1 * inv); o.z = f2bf(o2 * inv); o.w = f2bf(o3 * inv);
    *(ushort4*)(attn + (size_t)wid * DIMV + col) = o;
}

// ---------------- launcher ----------------

extern "C" void kernel_launch(void* const* d_in, const int* in_sizes, int n_in,
                              void* d_out, int out_size, void* d_ws, size_t ws_size,
                              hipStream_t stream) {
    const float* x  = (const float*)d_in[0];
    const float* Wq = (const float*)d_in[1];
    const float* bq = (const float*)d_in[2];
    const float* Wk = (const float*)d_in[3];
    const float* bk = (const float*)d_in[4];
    const float* Wv = (const float*)d_in[5];
    const float* bv = (const float*)d_in[6];
    const float* Wo = (const float*)d_in[7];
    const float* bo = (const float*)d_in[8];
    const int* src  = (const int*)d_in[9];
    const int* dst  = (const int*)d_in[10];
    int N = in_sizes[0] / DIMV;
    int E = in_sizes[9];
    float* out = (float*)d_out;

    char* p = (char*)d_ws;
    auto alloc = [&](size_t bytes) {
        char* r = p;
        p += (bytes + 255) & ~(size_t)255;
        return r;
    };
    unsigned short* Wcat = (unsigned short*)alloc((size_t)4 * 65536 * 2);   // [Wq|Wk|Wv|Wo] bf16
    unsigned short* QKV  = (unsigned short*)alloc((size_t)3 * N * DIMV * 2);
    unsigned short* attn = (unsigned short*)alloc((size_t)N * DIMV * 2);
    int* deg             = (int*)alloc((size_t)N * 4);
    int* offsets         = (int*)alloc((size_t)(N + 1) * 4);
    int* cursor          = (int*)alloc((size_t)N * 4);
    int* perm_src        = (int*)alloc((size_t)E * 4);
    int* bsum            = (int*)alloc((size_t)1024 * 4);

    // weight conversion (1 kernel, 4 matrices)
    dim3 gw(64, 4);
    cvt_w<<<gw, 256, 0, stream>>>(Wq, Wk, Wv, Wo, Wcat);

    // CSR build
    int nb = (N + 255) / 256;
    zero_i32<<<nb, 256, 0, stream>>>(deg, N);
    count_deg<<<(E + 255) / 256, 256, 0, stream>>>(dst, deg, E);
    block_sum<<<nb, 256, 0, stream>>>(deg, bsum, N);
    scan_bsum<<<1, 64, 0, stream>>>(bsum, nb);
    scan_final<<<nb, 256, 0, stream>>>(deg, bsum, offsets, cursor, N);
    scatter_edges<<<(E + 255) / 256, 256, 0, stream>>>(src, dst, cursor, perm_src, E);

    // fused QKV projection: x(f32) -> QKV(bf16), A read once, 24 weight tiles
    int gblocks = (N + 63) / 64;
    gemm_fused<true, false><<<gblocks, 256, 0, stream>>>(
        x, Wcat, bq, bk, bv, QKV, N, 24);

    const unsigned short* Qp = QKV;
    const unsigned short* Kp = QKV + (size_t)N * DIMV;
    const unsigned short* Vp = QKV + (size_t)2 * N * DIMV;
    node_attn<<<(N + 3) / 4, 256, 0, stream>>>(Qp, Kp, Vp, offsets, perm_src, attn, N);

    // output projection: attn(bf16) -> out(f32), 8 tiles (Wo slot = mat 3 of Wcat)
    gemm_fused<false, true><<<gblocks, 256, 0, stream>>>(
        attn, Wcat + (size_t)3 * 65536, bo, bo, bo, out, N, 8);
}